// Round 1
// baseline (587.123 us; speedup 1.0000x reference)
//
#include <hip/hip_runtime.h>
#include <math.h>

#define B 128
#define H 4
#define N 4096
#define W 128
#define CTRL (H*(3*W+6))   // 1560
#define EPSF 1e-8f

__device__ __forceinline__ float sigmoidf_(float x){ return 1.0f/(1.0f+expf(-x)); }
__device__ __forceinline__ float softplusf_(float x){ return (x>20.0f)? x : log1pf(expf(x)); }

// ---- block reduction helpers (256 threads = 4 waves of 64) ----
__device__ __forceinline__ float blockReduceSum256(float v, float* red){
  int tid = threadIdx.x;
  #pragma unroll
  for (int off=32; off>0; off>>=1) v += __shfl_xor(v, off);
  __syncthreads();                 // protect red reuse from prior call
  if ((tid&63)==0) red[tid>>6] = v;
  __syncthreads();
  return red[0]+red[1]+red[2]+red[3];
}
__device__ __forceinline__ float blockReduceMax256(float v, float* red){
  int tid = threadIdx.x;
  #pragma unroll
  for (int off=32; off>0; off>>=1) v = fmaxf(v, __shfl_xor(v, off));
  __syncthreads();
  if ((tid&63)==0) red[tid>>6] = v;
  __syncthreads();
  return fmaxf(fmaxf(red[0],red[1]), fmaxf(red[2],red[3]));
}

// ---- kernel 1: control prep ----
// grid = B*H blocks, 128 threads. Writes tanh(keys), sigmoid(erase), tanh(write),
// and per-(b,h) scalars {beta, gate, s0,s1,s2, gamma, knorm}.
__global__ __launch_bounds__(128) void prep_kernel(const float* __restrict__ controls,
    float* __restrict__ keys_t, float* __restrict__ erase_s, float* __restrict__ write_t,
    float* __restrict__ scal){
  int bh = blockIdx.x;
  int b = bh >> 2, h = bh & (H-1);
  int w = threadIdx.x;
  const float* c = controls + (size_t)b*CTRL;
  float k = tanhf(c[h*W + w]);
  keys_t [bh*W + w] = k;
  erase_s[bh*W + w] = sigmoidf_(c[1*H*W + h*W + w]);
  write_t[bh*W + w] = tanhf   (c[2*H*W + h*W + w]);
  __shared__ float red[128];
  red[w] = k*k;
  __syncthreads();
  for (int s=64; s>0; s>>=1){ if (w<s) red[w] += red[w+s]; __syncthreads(); }
  if (w==0){
    float knorm = sqrtf(red[0]);
    float beta  = softplusf_(c[3*H*W + h]);
    float gate  = sigmoidf_ (c[3*H*W + H + h]);
    float s0r = c[3*H*W + 2*H + h*3 + 0];
    float s1r = c[3*H*W + 2*H + h*3 + 1];
    float s2r = c[3*H*W + 2*H + h*3 + 2];
    float m = fmaxf(s0r, fmaxf(s1r, s2r));
    float e0 = expf(s0r-m), e1 = expf(s1r-m), e2 = expf(s2r-m);
    float inv = 1.0f/(e0+e1+e2);
    float gamma = 1.0f + softplusf_(c[3*H*W + 5*H + h]);
    float* sc = scal + bh*8;
    sc[0]=beta; sc[1]=gate; sc[2]=e0*inv; sc[3]=e1*inv; sc[4]=e2*inv; sc[5]=gamma; sc[6]=knorm;
  }
}

// ---- kernel 2: beta-scaled cosine scores [B,H,N] ----
// grid = (N/64, B), 256 threads = 4 waves; each wave handles one memory row per iter.
__global__ __launch_bounds__(256) void scores_kernel(const float* __restrict__ memory,
    const float* __restrict__ keys_t, const float* __restrict__ scal,
    float* __restrict__ scores){
  int b = blockIdx.y;
  int n0 = blockIdx.x * 64;
  int tid = threadIdx.x;
  int wave = tid >> 6, lane = tid & 63;
  __shared__ __align__(16) float kk[H][W];
  __shared__ float kbeta[H], kn[H];
  for (int i = tid; i < H*W; i += 256) kk[0][i] = keys_t[(size_t)b*H*W + i];
  if (tid < H){ kbeta[tid] = scal[(b*H+tid)*8 + 0]; kn[tid] = scal[(b*H+tid)*8 + 6]; }
  __syncthreads();
  for (int i = wave; i < 64; i += 4){
    int n = n0 + i;
    const float2 m = ((const float2*)(memory + ((size_t)b*N + n)*W))[lane];
    float msq = m.x*m.x + m.y*m.y;
    float d0 = m.x*kk[0][2*lane] + m.y*kk[0][2*lane+1];
    float d1 = m.x*kk[1][2*lane] + m.y*kk[1][2*lane+1];
    float d2 = m.x*kk[2][2*lane] + m.y*kk[2][2*lane+1];
    float d3 = m.x*kk[3][2*lane] + m.y*kk[3][2*lane+1];
    #pragma unroll
    for (int off=32; off>0; off>>=1){
      msq += __shfl_xor(msq, off);
      d0  += __shfl_xor(d0 , off);
      d1  += __shfl_xor(d1 , off);
      d2  += __shfl_xor(d2 , off);
      d3  += __shfl_xor(d3 , off);
    }
    if (lane == 0){
      float mn = sqrtf(msq);
      scores[((size_t)(b*H+0))*N + n] = kbeta[0]*d0/(kn[0]*mn + EPSF);
      scores[((size_t)(b*H+1))*N + n] = kbeta[1]*d1/(kn[1]*mn + EPSF);
      scores[((size_t)(b*H+2))*N + n] = kbeta[2]*d2/(kn[2]*mn + EPSF);
      scores[((size_t)(b*H+3))*N + n] = kbeta[3]*d3/(kn[3]*mn + EPSF);
    }
  }
}

// ---- kernel 3: softmax -> interp -> circular conv -> sharpen -> write_dist ----
// grid = B*H blocks, 256 threads, 16 elements/thread. wd may alias scores:
// every read of the scores row happens before any write of the wd row (same block).
__global__ __launch_bounds__(256) void dist_kernel(const float* scores,
    const float* __restrict__ bias, const float* __restrict__ scal, float* wd){
  int bh = blockIdx.x;
  int h = bh & (H-1);
  int tid = threadIdx.x;
  __shared__ float buf[N];    // 16 KB
  __shared__ float red[4];
  const float* srow = scores + (size_t)bh*N;

  float v[16]; float lmax = -1e30f;
  #pragma unroll
  for (int i=0;i<16;i++){ v[i] = srow[tid + 256*i]; lmax = fmaxf(lmax, v[i]); }
  float smax = blockReduceMax256(lmax, red);
  float lsum = 0.0f;
  #pragma unroll
  for (int i=0;i<16;i++){ v[i] = expf(v[i]-smax); lsum += v[i]; }
  float ssum = blockReduceSum256(lsum, red);

  const float* brow = bias + (size_t)h*N;
  float p[16]; float bl = -1e30f;
  #pragma unroll
  for (int i=0;i<16;i++){ p[i] = brow[tid + 256*i]; bl = fmaxf(bl, p[i]); }
  float bmax = blockReduceMax256(bl, red);
  float bls = 0.0f;
  #pragma unroll
  for (int i=0;i<16;i++){ p[i] = expf(p[i]-bmax); bls += p[i]; }
  float bsum = blockReduceSum256(bls, red);

  float gate = scal[bh*8+1];
  float invs = 1.0f/ssum, invb = 1.0f/bsum;
  #pragma unroll
  for (int i=0;i<16;i++)
    buf[tid + 256*i] = gate*v[i]*invs + (1.0f-gate)*p[i]*invb;
  __syncthreads();

  float s0 = scal[bh*8+2], s1 = scal[bh*8+3], s2 = scal[bh*8+4], gamma = scal[bh*8+5];
  float q[16]; float qsum = 0.0f;
  #pragma unroll
  for (int i=0;i<16;i++){
    int n = tid + 256*i;
    float wm = buf[(n + N - 1) & (N-1)];
    float wc = buf[n];
    float wp = buf[(n + 1) & (N-1)];
    float wsft = s0*wm + s1*wc + s2*wp;   // strictly > 0
    float pw = powf(wsft, gamma);
    q[i] = pw; qsum += pw;
  }
  float tot = blockReduceSum256(qsum, red);
  float inv = 1.0f/(tot + EPSF);
  float* wrow = wd + (size_t)bh*N;
  #pragma unroll
  for (int i=0;i<16;i++) wrow[tid + 256*i] = q[i]*inv;
}

// ---- kernel 4: out = memory * prod_h(1 - wd*erase) + sum_h wd*write ----
// grid = (N/64, B), 256 threads, float4 I/O, erase/write staged in LDS.
__global__ __launch_bounds__(256) void final_kernel(const float* __restrict__ memory,
    const float* __restrict__ wd, const float* __restrict__ erase_s,
    const float* __restrict__ write_t, float* __restrict__ out){
  int b = blockIdx.y;
  int tid = threadIdx.x;
  __shared__ __align__(16) float esh[H][W];
  __shared__ __align__(16) float wsh[H][W];
  for (int i=tid;i<H*W;i+=256){ esh[0][i] = erase_s[(size_t)b*H*W+i]; wsh[0][i] = write_t[(size_t)b*H*W+i]; }
  __syncthreads();
  int wq = (tid & 31) * 4;   // float4 column
  int rl = tid >> 5;         // row-in-group 0..7
  int n0 = blockIdx.x * 64;
  for (int r = rl; r < 64; r += 8){
    int n = n0 + r;
    size_t base = ((size_t)b*N + n)*W + wq;
    float4 m = *(const float4*)(memory + base);
    float wdv[4];
    #pragma unroll
    for (int h=0;h<H;h++) wdv[h] = wd[((size_t)(b*H+h))*N + n];
    float4 prod = make_float4(1.f,1.f,1.f,1.f);
    float4 upd  = make_float4(0.f,0.f,0.f,0.f);
    #pragma unroll
    for (int h=0;h<H;h++){
      float4 e  = *(const float4*)&esh[h][wq];
      float4 wv = *(const float4*)&wsh[h][wq];
      float d = wdv[h];
      prod.x *= 1.0f - d*e.x;  prod.y *= 1.0f - d*e.y;
      prod.z *= 1.0f - d*e.z;  prod.w *= 1.0f - d*e.w;
      upd.x += d*wv.x;  upd.y += d*wv.y;  upd.z += d*wv.z;  upd.w += d*wv.w;
    }
    float4 o;
    o.x = m.x*prod.x + upd.x;  o.y = m.y*prod.y + upd.y;
    o.z = m.z*prod.z + upd.z;  o.w = m.w*prod.w + upd.w;
    *(float4*)(out + base) = o;
  }
}

extern "C" void kernel_launch(void* const* d_in, const int* in_sizes, int n_in,
                              void* d_out, int out_size, void* d_ws, size_t ws_size,
                              hipStream_t stream){
  const float* memory   = (const float*)d_in[0];
  const float* controls = (const float*)d_in[1];
  const float* bias     = (const float*)d_in[2];
  float* out = (float*)d_out;

  float* ws      = (float*)d_ws;
  float* keys_t  = ws;                    // B*H*W
  float* erase_s = keys_t  + B*H*W;       // B*H*W
  float* write_t = erase_s + B*H*W;       // B*H*W
  float* scal    = write_t + B*H*W;       // B*H*8
  float* scores  = scal    + B*H*8;       // B*H*N
  float* wd      = scores;                // aliased over scores (safe, see dist_kernel)
  // total ws use: 3*65536 + 4096 + 2097152 floats ≈ 9.45 MB

  prep_kernel  <<<dim3(B*H),      dim3(W),   0, stream>>>(controls, keys_t, erase_s, write_t, scal);
  scores_kernel<<<dim3(N/64, B),  dim3(256), 0, stream>>>(memory, keys_t, scal, scores);
  dist_kernel  <<<dim3(B*H),      dim3(256), 0, stream>>>(scores, bias, scal, wd);
  final_kernel <<<dim3(N/64, B),  dim3(256), 0, stream>>>(memory, wd, erase_s, write_t, out);
}